// Round 12
// baseline (47.019 us; speedup 1.0000x reference)
//
#include <hip/hip_runtime.h>
#include <hip/hip_bf16.h>

// LocallyConnected1d: x (64,64,1024) f32, weights (1024,64,64,9) f32, bias (64,1024) f32
// out[b*65536 + w*64 + o] = sum_{c,t} x[b,c,w+t-4] * weights[w,o,c,t] + bias_flat[w*64+o]
// Round 12 = round 11 with PFD 6->9 (full-phase weight pipeline in registers), funded by
// dropping the phase-1 Xt preload (Xt is L2-resident; exposed reload ~0.1us/block).
// Experiment: is the 151MB weight stream issue-depth-limited or BW-bound?
// Prepass: x -> Xt[pos+4][b][c] bf16 (8.45MB, zero-padded), one tile per block.
// Main: per-w GEMM M=64,N=64,K=576; lgkm-only barriers keep the stream in flight;
// A staged via reg-transpose + ds_write_b128; XCD-contiguous w mapping (r6: -14us).
// Falsified: device spin barrier (r9, -7x), direct-from-x staging (r8 line-request wall),
// NT weight loads (r10, 4x line amplification), setprio (r10).

typedef __bf16 bf16x8 __attribute__((ext_vector_type(8)));
typedef float  f32x4  __attribute__((ext_vector_type(4)));

#define NK    576
#define LDAP  296                      // 288 + 8 pad (per-phase panel)
#define NCH   18
#define PFD   9                        // full phase in flight
#define XT_SLABS 1032                  // pos -4 .. 1027 stored at pos+4
#define XT_BYTES ((size_t)XT_SLABS * 4096 * 2)

// barrier that does NOT drain vmcnt (keeps weight prefetch in flight)
#define LGKM_BAR() asm volatile("s_waitcnt lgkmcnt(0)\n\ts_barrier" ::: "memory")

// ---------------- pre-pass: Xt[p+4][b][c] = bf16(x[b][c][p]) ----------------
__global__ __launch_bounds__(256)
void xt_transpose_kernel(const float* __restrict__ x, __bf16* __restrict__ xt) {
    const int tid = threadIdx.x;
    if (blockIdx.x >= 2048) {
        const int s    = blockIdx.x - 2048;              // 0..7
        const int slab = (s < 4) ? s : (1024 + s);       // 0..3, 1028..1031
        f32x4* p = reinterpret_cast<f32x4*>(xt + (size_t)slab * 4096);
        const f32x4 z = (f32x4){0.f, 0.f, 0.f, 0.f};
        p[tid] = z;
        p[256 + tid] = z;
        return;
    }
    __shared__ float T[64][33];
    const int b  = blockIdx.x >> 5;          // 0..63
    const int p0 = (blockIdx.x & 31) * 32;   // 0,32,..,992

    const int c = tid >> 2;
    const int q = tid & 3;
    const float* src = x + (((size_t)(b * 64 + c)) << 10) + p0 + q * 8;
    f32x4 v0 = *reinterpret_cast<const f32x4*>(src);
    f32x4 v1 = *reinterpret_cast<const f32x4*>(src + 4);
    #pragma unroll
    for (int i = 0; i < 4; ++i) { T[c][q * 8 + i] = v0[i]; T[c][q * 8 + 4 + i] = v1[i]; }
    __syncthreads();

    const int pl = tid >> 3;                 // 0..31
    const int cg = tid & 7;                  // 0..7
    bf16x8 o8;
    #pragma unroll
    for (int i = 0; i < 8; ++i) o8[i] = (__bf16)T[cg * 8 + i][pl];
    *reinterpret_cast<bf16x8*>(xt + (size_t)(p0 + pl + 4) * 4096 + b * 64 + cg * 8) = o8;
}

// ---------------- main kernel ----------------
__global__ __launch_bounds__(256, 4)
void lc1d_main_kernel(const __bf16* __restrict__ xt,
                      const float* __restrict__ wts,
                      const float* __restrict__ bias,
                      float* __restrict__ out) {
    __shared__ __bf16 Alds[64][LDAP];

    // XCD-contiguous w mapping (1024 = 8 XCD * 128)
    const int orig = blockIdx.x;
    const int w    = ((orig & 7) << 7) | (orig >> 3);

    const int tid  = threadIdx.x;
    const int lane = tid & 63;
    const int wv   = tid >> 6;
    const int m16  = lane & 15;
    const int ko   = (lane >> 4) * 8;
    const int o    = wv * 16 + m16;

    const float* wbase = wts + (size_t)w * (64 * NK) + (size_t)o * NK + ko;
    const float bv = bias[w * 64 + o];       // hoisted epilogue bias

    const int sb  = tid >> 2;
    const int sc8 = (tid & 3) * 8;
    const __bf16* xtb = xt + (size_t)w * 4096 + sb * 64 + sc8;

    // ---- issue phase-0 Xt loads ----
    bf16x8 v[9];
    #pragma unroll
    for (int t = 0; t < 9; ++t)
        v[t] = *reinterpret_cast<const bf16x8*>(xtb + (size_t)t * 4096);

    // ---- full-phase weight prefetch pipeline (9 chunks = 72 VGPR in flight) ----
    f32x4 wr0[PFD], wr1[PFD];
    #pragma unroll
    for (int p = 0; p < PFD; ++p) {
        wr0[p] = *reinterpret_cast<const f32x4*>(wbase + p * 32);
        wr1[p] = *reinterpret_cast<const f32x4*>(wbase + p * 32 + 4);
    }

    // ---- transpose + write phase 0 ----
    {
        __bf16* dst = &Alds[sb][sc8 * 9];
        #pragma unroll
        for (int qq = 0; qq < 9; ++qq) {
            bf16x8 u;
            #pragma unroll
            for (int j = 0; j < 8; ++j) { int n = qq * 8 + j; u[j] = v[n % 9][n / 9]; }
            *reinterpret_cast<bf16x8*>(dst + qq * 8) = u;
        }
    }
    LGKM_BAR();

    f32x4 acc[4];
    #pragma unroll
    for (int i = 0; i < 4; ++i) acc[i] = (f32x4){0.f, 0.f, 0.f, 0.f};

    // ---- phase 0 MFMA: chunks 0..8, refill slot with chunk it+9 ----
    #pragma unroll
    for (int it = 0; it < 9; ++it) {
        f32x4 u0 = wr0[it], u1 = wr1[it];
        wr0[it] = *reinterpret_cast<const f32x4*>(wbase + (it + 9) * 32);
        wr1[it] = *reinterpret_cast<const f32x4*>(wbase + (it + 9) * 32 + 4);
        bf16x8 bf;
        #pragma unroll
        for (int j = 0; j < 4; ++j) { bf[j] = (__bf16)u0[j]; bf[j + 4] = (__bf16)u1[j]; }
        const int kk0 = it * 32;
        #pragma unroll
        for (int bt = 0; bt < 4; ++bt) {
            bf16x8 af = *reinterpret_cast<const bf16x8*>(&Alds[bt * 16 + m16][kk0 + ko]);
            acc[bt] = __builtin_amdgcn_mfma_f32_16x16x32_bf16(af, bf, acc[bt], 0, 0, 0);
        }
    }

    LGKM_BAR();   // WAR: all waves done reading phase-0 panel

    // ---- phase 1 staging (Xt loads here; L2-resident, latency exposed once) ----
    #pragma unroll
    for (int t = 0; t < 9; ++t)
        v[t] = *reinterpret_cast<const bf16x8*>(xtb + 32 + (size_t)t * 4096);
    {
        __bf16* dst = &Alds[sb][sc8 * 9];
        #pragma unroll
        for (int qq = 0; qq < 9; ++qq) {
            bf16x8 u;
            #pragma unroll
            for (int j = 0; j < 8; ++j) { int n = qq * 8 + j; u[j] = v[n % 9][n / 9]; }
            *reinterpret_cast<bf16x8*>(dst + qq * 8) = u;
        }
    }
    LGKM_BAR();

    // ---- phase 1 MFMA: chunks 9..17 (all already in registers) ----
    #pragma unroll
    for (int it = 9; it < NCH; ++it) {
        f32x4 u0 = wr0[it - 9], u1 = wr1[it - 9];
        bf16x8 bf;
        #pragma unroll
        for (int j = 0; j < 4; ++j) { bf[j] = (__bf16)u0[j]; bf[j + 4] = (__bf16)u1[j]; }
        const int kk0 = (it - 9) * 32;
        #pragma unroll
        for (int bt = 0; bt < 4; ++bt) {
            bf16x8 af = *reinterpret_cast<const bf16x8*>(&Alds[bt * 16 + m16][kk0 + ko]);
            acc[bt] = __builtin_amdgcn_mfma_f32_16x16x32_bf16(af, bf, acc[bt], 0, 0, 0);
        }
    }

    // ---- epilogue: NT stores (write-once output) ----
    const int r0 = (lane >> 4) * 4;
    float* outp = out + (size_t)w * 64 + o;
    #pragma unroll
    for (int bt = 0; bt < 4; ++bt) {
        #pragma unroll
        for (int r = 0; r < 4; ++r) {
            int b = bt * 16 + r0 + r;
            __builtin_nontemporal_store(acc[bt][r] + bv, &outp[(size_t)b * 65536]);
        }
    }
}

// ---------------- fallback (round-2 proven, used if ws too small) ----------------
__global__ __launch_bounds__(256, 4)
void lc1d_fallback_kernel(const float* __restrict__ x,
                          const float* __restrict__ wts,
                          const float* __restrict__ bias,
                          float* __restrict__ out) {
    __shared__ __bf16 Alds[64][LDAP];
    const int w    = blockIdx.x;
    const int tid  = threadIdx.x;
    const int lane = tid & 63;
    const int wv   = tid >> 6;
    const int m16  = lane & 15;
    const int ko   = (lane >> 4) * 8;
    const int o    = wv * 16 + m16;
    const float* wbase = wts + (size_t)w * (64 * NK) + (size_t)o * NK + ko;
    const int xbase  = w - 4;
    const int a0     = xbase & ~3;
    const int d      = xbase - a0;
    const int rowsel = tid >> 2;
    const int sl     = tid & 3;
    const int p0     = a0 + sl * 4;
    const bool inb   = ((unsigned)p0 < 1024u);

    f32x4 acc[4];
    #pragma unroll
    for (int i = 0; i < 4; ++i) acc[i] = (f32x4){0.f, 0.f, 0.f, 0.f};

    #pragma unroll
    for (int ph = 0; ph < 2; ++ph) {
        f32x4 wr[18];
        const float* wp = wbase + ph * 288;
        #pragma unroll
        for (int it = 0; it < 9; ++it) {
            wr[2 * it]     = *reinterpret_cast<const f32x4*>(wp + it * 32);
            wr[2 * it + 1] = *reinterpret_cast<const f32x4*>(wp + it * 32 + 4);
        }
        if (ph) __syncthreads();
        #pragma unroll 4
        for (int i = 0; i < 32; ++i) {
            int R  = i * 64 + rowsel;
            int c  = R & 31;
            int b  = R >> 5;
            int cc = ph * 32 + c;
            f32x4 vv = (f32x4){0.f, 0.f, 0.f, 0.f};
            if (inb) vv = *reinterpret_cast<const f32x4*>(x + (((size_t)(b * 64 + cc)) << 10) + p0);
            __bf16* dst = &Alds[b][c * 9];
            #pragma unroll
            for (int j = 0; j < 4; ++j) {
                int t = sl * 4 + j - d;
                if (t >= 0 && t <= 8) dst[t] = (__bf16)vv[j];
            }
        }
        __syncthreads();
        #pragma unroll
        for (int it = 0; it < 9; ++it) {
            bf16x8 bf;
            #pragma unroll
            for (int j = 0; j < 4; ++j) { bf[j] = (__bf16)wr[2 * it][j]; bf[j + 4] = (__bf16)wr[2 * it + 1][j]; }
            const int kk0 = it * 32;
            #pragma unroll
            for (int bt = 0; bt < 4; ++bt) {
                bf16x8 af = *reinterpret_cast<const bf16x8*>(&Alds[bt * 16 + m16][kk0 + ko]);
                acc[bt] = __builtin_amdgcn_mfma_f32_16x16x32_bf16(af, bf, acc[bt], 0, 0, 0);
            }
        }
    }
    const float bv = bias[w * 64 + o];
    const int r0 = (lane >> 4) * 4;
    float* outp = out + (size_t)w * 64 + o;
    #pragma unroll
    for (int bt = 0; bt < 4; ++bt) {
        #pragma unroll
        for (int r = 0; r < 4; ++r) {
            int b = bt * 16 + r0 + r;
            outp[(size_t)b * 65536] = acc[bt][r] + bv;
        }
    }
}

extern "C" void kernel_launch(void* const* d_in, const int* in_sizes, int n_in,
                              void* d_out, int out_size, void* d_ws, size_t ws_size,
                              hipStream_t stream) {
    const float* x    = (const float*)d_in[0];
    const float* wts  = (const float*)d_in[1];
    const float* bias = (const float*)d_in[2];
    float* out = (float*)d_out;

    if (ws_size >= XT_BYTES) {
        __bf16* xt = (__bf16*)d_ws;
        xt_transpose_kernel<<<dim3(2056), dim3(256), 0, stream>>>(x, xt);
        lc1d_main_kernel<<<dim3(1024), dim3(256), 0, stream>>>(xt, wts, bias, out);
    } else {
        lc1d_fallback_kernel<<<dim3(1024), dim3(256), 0, stream>>>(x, wts, bias, out);
    }
}

// Round 13
// 39.659 us; speedup vs baseline: 1.1856x; 1.1856x over previous
//
#include <hip/hip_runtime.h>
#include <hip/hip_bf16.h>

// LocallyConnected1d: x (64,64,1024) f32, weights (1024,64,64,9) f32, bias (64,1024) f32
// out[b*65536 + w*64 + o] = sum_{c,t} x[b,c,w+t-4] * weights[w,o,c,t] + bias_flat[w*64+o]
// FINAL (= round 11, proven 39.76us twice):
// Prepass: x -> Xt[pos+4][b][c] bf16 (8.45MB, zero-padded), one 32-pos tile per block.
// Main: per-w GEMM M=64,N=64,K=576; 151MB read-once fp32 weight stream with 6-deep
// rolling register prefetch that survives lgkm-only barriers; A staged from Xt via
// reg-transpose + ds_write_b128; phase-1 Xt preload hidden under phase-0 MFMA;
// XCD-contiguous w mapping keeps Xt per-XCD-L2-resident; NT stores for out.
// Empirically falsified routes: 1-phase big tile (r3: occupancy+L2 thrash),
// direct-from-x staging (r8: TA line-request wall), device spin barrier (r9: -7x
// cross-XCD line ping-pong), NT weight loads (r10: line-reuse defeat, +17us),
// setprio (r10), PFD=9 w/ serial phase-1 staging (r12: +7us).

typedef __bf16 bf16x8 __attribute__((ext_vector_type(8)));
typedef float  f32x4  __attribute__((ext_vector_type(4)));

#define NK    576
#define LDAP  296                      // 288 + 8 pad (per-phase panel)
#define NCH   18
#define PFD   6
#define XT_SLABS 1032                  // pos -4 .. 1027 stored at pos+4
#define XT_BYTES ((size_t)XT_SLABS * 4096 * 2)

// barrier that does NOT drain vmcnt (keeps weight prefetch in flight)
#define LGKM_BAR() asm volatile("s_waitcnt lgkmcnt(0)\n\ts_barrier" ::: "memory")

// ---------------- pre-pass: Xt[p+4][b][c] = bf16(x[b][c][p]) ----------------
__global__ __launch_bounds__(256)
void xt_transpose_kernel(const float* __restrict__ x, __bf16* __restrict__ xt) {
    const int tid = threadIdx.x;
    if (blockIdx.x >= 2048) {
        const int s    = blockIdx.x - 2048;              // 0..7
        const int slab = (s < 4) ? s : (1024 + s);       // 0..3, 1028..1031
        f32x4* p = reinterpret_cast<f32x4*>(xt + (size_t)slab * 4096);
        const f32x4 z = (f32x4){0.f, 0.f, 0.f, 0.f};
        p[tid] = z;
        p[256 + tid] = z;
        return;
    }
    __shared__ float T[64][33];
    const int b  = blockIdx.x >> 5;          // 0..63
    const int p0 = (blockIdx.x & 31) * 32;   // 0,32,..,992

    const int c = tid >> 2;
    const int q = tid & 3;
    const float* src = x + (((size_t)(b * 64 + c)) << 10) + p0 + q * 8;
    f32x4 v0 = *reinterpret_cast<const f32x4*>(src);
    f32x4 v1 = *reinterpret_cast<const f32x4*>(src + 4);
    #pragma unroll
    for (int i = 0; i < 4; ++i) { T[c][q * 8 + i] = v0[i]; T[c][q * 8 + 4 + i] = v1[i]; }
    __syncthreads();

    const int pl = tid >> 3;                 // 0..31
    const int cg = tid & 7;                  // 0..7
    bf16x8 o8;
    #pragma unroll
    for (int i = 0; i < 8; ++i) o8[i] = (__bf16)T[cg * 8 + i][pl];
    *reinterpret_cast<bf16x8*>(xt + (size_t)(p0 + pl + 4) * 4096 + b * 64 + cg * 8) = o8;
}

// ---------------- main kernel ----------------
__global__ __launch_bounds__(256, 4)
void lc1d_main_kernel(const __bf16* __restrict__ xt,
                      const float* __restrict__ wts,
                      const float* __restrict__ bias,
                      float* __restrict__ out) {
    __shared__ __bf16 Alds[64][LDAP];

    // XCD-contiguous w mapping (1024 = 8 XCD * 128): Xt slabs reused by 9 neighbor w
    // stay in the local 4MB L2.
    const int orig = blockIdx.x;
    const int w    = ((orig & 7) << 7) | (orig >> 3);

    const int tid  = threadIdx.x;
    const int lane = tid & 63;
    const int wv   = tid >> 6;
    const int m16  = lane & 15;
    const int ko   = (lane >> 4) * 8;
    const int o    = wv * 16 + m16;

    const float* wbase = wts + (size_t)w * (64 * NK) + (size_t)o * NK + ko;
    const float bv = bias[w * 64 + o];       // hoisted epilogue bias

    const int sb  = tid >> 2;
    const int sc8 = (tid & 3) * 8;
    const __bf16* xtb = xt + (size_t)w * 4096 + sb * 64 + sc8;

    // ---- issue phase-0 Xt loads ----
    bf16x8 v[9];
    #pragma unroll
    for (int t = 0; t < 9; ++t)
        v[t] = *reinterpret_cast<const bf16x8*>(xtb + (size_t)t * 4096);

    // ---- start weight prefetch pipeline (plain loads; L3-resident across replays) ----
    f32x4 wr0[PFD], wr1[PFD];
    #pragma unroll
    for (int p = 0; p < PFD; ++p) {
        wr0[p] = *reinterpret_cast<const f32x4*>(wbase + p * 32);
        wr1[p] = *reinterpret_cast<const f32x4*>(wbase + p * 32 + 4);
    }

    // ---- transpose + write phase 0 ----
    {
        __bf16* dst = &Alds[sb][sc8 * 9];
        #pragma unroll
        for (int qq = 0; qq < 9; ++qq) {
            bf16x8 u;
            #pragma unroll
            for (int j = 0; j < 8; ++j) { int n = qq * 8 + j; u[j] = v[n % 9][n / 9]; }
            *reinterpret_cast<bf16x8*>(dst + qq * 8) = u;
        }
    }
    LGKM_BAR();

    f32x4 acc[4];
    #pragma unroll
    for (int i = 0; i < 4; ++i) acc[i] = (f32x4){0.f, 0.f, 0.f, 0.f};

    // ---- issue phase-1 Xt loads (hidden under phase-0 MFMA; written after WAR barrier) ----
    #pragma unroll
    for (int t = 0; t < 9; ++t)
        v[t] = *reinterpret_cast<const bf16x8*>(xtb + 32 + (size_t)t * 4096);

    // ---- phase 0 MFMA: chunks 0..8 ----
    #pragma unroll
    for (int it = 0; it < 9; ++it) {
        const int s = it % PFD;
        f32x4 u0 = wr0[s], u1 = wr1[s];
        wr0[s] = *reinterpret_cast<const f32x4*>(wbase + (it + PFD) * 32);
        wr1[s] = *reinterpret_cast<const f32x4*>(wbase + (it + PFD) * 32 + 4);
        bf16x8 bf;
        #pragma unroll
        for (int j = 0; j < 4; ++j) { bf[j] = (__bf16)u0[j]; bf[j + 4] = (__bf16)u1[j]; }
        const int kk0 = it * 32;
        #pragma unroll
        for (int bt = 0; bt < 4; ++bt) {
            bf16x8 af = *reinterpret_cast<const bf16x8*>(&Alds[bt * 16 + m16][kk0 + ko]);
            acc[bt] = __builtin_amdgcn_mfma_f32_16x16x32_bf16(af, bf, acc[bt], 0, 0, 0);
        }
    }

    LGKM_BAR();   // WAR: all waves done reading phase-0 panel

    // ---- transpose + write phase 1 ----
    {
        __bf16* dst = &Alds[sb][sc8 * 9];
        #pragma unroll
        for (int qq = 0; qq < 9; ++qq) {
            bf16x8 u;
            #pragma unroll
            for (int j = 0; j < 8; ++j) { int n = qq * 8 + j; u[j] = v[n % 9][n / 9]; }
            *reinterpret_cast<bf16x8*>(dst + qq * 8) = u;
        }
    }
    LGKM_BAR();

    // ---- phase 1 MFMA: chunks 9..17 ----
    #pragma unroll
    for (int it = 9; it < NCH; ++it) {
        const int s = it % PFD;
        f32x4 u0 = wr0[s], u1 = wr1[s];
        if (it + PFD < NCH) {
            wr0[s] = *reinterpret_cast<const f32x4*>(wbase + (it + PFD) * 32);
            wr1[s] = *reinterpret_cast<const f32x4*>(wbase + (it + PFD) * 32 + 4);
        }
        bf16x8 bf;
        #pragma unroll
        for (int j = 0; j < 4; ++j) { bf[j] = (__bf16)u0[j]; bf[j + 4] = (__bf16)u1[j]; }
        const int kk0 = (it - 9) * 32;
        #pragma unroll
        for (int bt = 0; bt < 4; ++bt) {
            bf16x8 af = *reinterpret_cast<const bf16x8*>(&Alds[bt * 16 + m16][kk0 + ko]);
            acc[bt] = __builtin_amdgcn_mfma_f32_16x16x32_bf16(af, bf, acc[bt], 0, 0, 0);
        }
    }

    // ---- epilogue: NT stores (write-once output) ----
    const int r0 = (lane >> 4) * 4;
    float* outp = out + (size_t)w * 64 + o;
    #pragma unroll
    for (int bt = 0; bt < 4; ++bt) {
        #pragma unroll
        for (int r = 0; r < 4; ++r) {
            int b = bt * 16 + r0 + r;
            __builtin_nontemporal_store(acc[bt][r] + bv, &outp[(size_t)b * 65536]);
        }
    }
}

// ---------------- fallback (round-2 proven, used if ws too small) ----------------
__global__ __launch_bounds__(256, 4)
void lc1d_fallback_kernel(const float* __restrict__ x,
                          const float* __restrict__ wts,
                          const float* __restrict__ bias,
                          float* __restrict__ out) {
    __shared__ __bf16 Alds[64][LDAP];
    const int w    = blockIdx.x;
    const int tid  = threadIdx.x;
    const int lane = tid & 63;
    const int wv   = tid >> 6;
    const int m16  = lane & 15;
    const int ko   = (lane >> 4) * 8;
    const int o    = wv * 16 + m16;
    const float* wbase = wts + (size_t)w * (64 * NK) + (size_t)o * NK + ko;
    const int xbase  = w - 4;
    const int a0     = xbase & ~3;
    const int d      = xbase - a0;
    const int rowsel = tid >> 2;
    const int sl     = tid & 3;
    const int p0     = a0 + sl * 4;
    const bool inb   = ((unsigned)p0 < 1024u);

    f32x4 acc[4];
    #pragma unroll
    for (int i = 0; i < 4; ++i) acc[i] = (f32x4){0.f, 0.f, 0.f, 0.f};

    #pragma unroll
    for (int ph = 0; ph < 2; ++ph) {
        f32x4 wr[18];
        const float* wp = wbase + ph * 288;
        #pragma unroll
        for (int it = 0; it < 9; ++it) {
            wr[2 * it]     = *reinterpret_cast<const f32x4*>(wp + it * 32);
            wr[2 * it + 1] = *reinterpret_cast<const f32x4*>(wp + it * 32 + 4);
        }
        if (ph) __syncthreads();
        #pragma unroll 4
        for (int i = 0; i < 32; ++i) {
            int R  = i * 64 + rowsel;
            int c  = R & 31;
            int b  = R >> 5;
            int cc = ph * 32 + c;
            f32x4 vv = (f32x4){0.f, 0.f, 0.f, 0.f};
            if (inb) vv = *reinterpret_cast<const f32x4*>(x + (((size_t)(b * 64 + cc)) << 10) + p0);
            __bf16* dst = &Alds[b][c * 9];
            #pragma unroll
            for (int j = 0; j < 4; ++j) {
                int t = sl * 4 + j - d;
                if (t >= 0 && t <= 8) dst[t] = (__bf16)vv[j];
            }
        }
        __syncthreads();
        #pragma unroll
        for (int it = 0; it < 9; ++it) {
            bf16x8 bf;
            #pragma unroll
            for (int j = 0; j < 4; ++j) { bf[j] = (__bf16)wr[2 * it][j]; bf[j + 4] = (__bf16)wr[2 * it + 1][j]; }
            const int kk0 = it * 32;
            #pragma unroll
            for (int bt = 0; bt < 4; ++bt) {
                bf16x8 af = *reinterpret_cast<const bf16x8*>(&Alds[bt * 16 + m16][kk0 + ko]);
                acc[bt] = __builtin_amdgcn_mfma_f32_16x16x32_bf16(af, bf, acc[bt], 0, 0, 0);
            }
        }
    }
    const float bv = bias[w * 64 + o];
    const int r0 = (lane >> 4) * 4;
    float* outp = out + (size_t)w * 64 + o;
    #pragma unroll
    for (int bt = 0; bt < 4; ++bt) {
        #pragma unroll
        for (int r = 0; r < 4; ++r) {
            int b = bt * 16 + r0 + r;
            outp[(size_t)b * 65536] = acc[bt][r] + bv;
        }
    }
}

extern "C" void kernel_launch(void* const* d_in, const int* in_sizes, int n_in,
                              void* d_out, int out_size, void* d_ws, size_t ws_size,
                              hipStream_t stream) {
    const float* x    = (const float*)d_in[0];
    const float* wts  = (const float*)d_in[1];
    const float* bias = (const float*)d_in[2];
    float* out = (float*)d_out;

    if (ws_size >= XT_BYTES) {
        __bf16* xt = (__bf16*)d_ws;
        xt_transpose_kernel<<<dim3(2056), dim3(256), 0, stream>>>(x, xt);
        lc1d_main_kernel<<<dim3(1024), dim3(256), 0, stream>>>(xt, wts, bias, out);
    } else {
        lc1d_fallback_kernel<<<dim3(1024), dim3(256), 0, stream>>>(x, wts, bias, out);
    }
}